// Round 1
// baseline (333.598 us; speedup 1.0000x reference)
//
#include <hip/hip_runtime.h>
#include <hip/hip_bf16.h>
#include <math.h>

#define KNN 5
#define SEARCH 3
#define K3 27
#define CENTER 13
#define NCLASSES 21
#define DIM_D 32
#define DIM_H 128
#define DIM_W 2048

__global__ __launch_bounds__(256) void bev_knn_kernel(
    const float* __restrict__ pr,   // proj_range  [D,H,W]
    const float* __restrict__ ur,   // unproj_range [P]
    const int*   __restrict__ pa,   // proj_argmax [D,H,W]
    const int*   __restrict__ px,
    const int*   __restrict__ py,
    const int*   __restrict__ pz,
    int*         __restrict__ out,
    int P)
{
    int p = blockIdx.x * blockDim.x + threadIdx.x;
    if (p >= P) return;

    float u = ur[p];
    int x = px[p], y = py[p], z = pz[p];

    // ---- gather 27 neighbor ranges (clamped addr + select; full MLP) ----
    float dist[K3];
#pragma unroll
    for (int k = 0; k < K3; ++k) {
        const int dz = k / 9 - 1;
        const int dy = (k / 3) % 3 - 1;
        const int dx = k % 3 - 1;
        int zz = z + dz, yy = y + dy, xx = x + dx;
        bool ok = ((unsigned)zz < (unsigned)DIM_D) &
                  ((unsigned)yy < (unsigned)DIM_H) &
                  ((unsigned)xx < (unsigned)DIM_W);
        int zi = ok ? zz : 0;
        int yi = ok ? yy : 0;
        int xi = ok ? xx : 0;
        float r = pr[((size_t)zi * DIM_H + yi) * DIM_W + xi];
        r = ok ? r : 0.0f;              // zero padding
        r = (r < 0.0f) ? INFINITY : r;  // negative-range mask
        float d = fabsf(r - u);
        dist[k] = (k == CENTER) ? 0.0f : d;
    }

    // ---- top-5 smallest, ties -> lower flat index (lax.top_k semantics) ----
    float bd[KNN];
    int   bk[KNN];
#pragma unroll
    for (int j = 0; j < KNN; ++j) { bd[j] = INFINITY; bk[j] = -1; }
#pragma unroll
    for (int k = 0; k < K3; ++k) {
        float dcur = dist[k];
        int   kcur = k;
#pragma unroll
        for (int j = 0; j < KNN; ++j) {
            // strict <: equal distances keep the earlier index in front
            bool take = dcur < bd[j];
            float td = bd[j]; int tk = bk[j];
            bd[j] = take ? dcur : bd[j];
            bk[j] = take ? kcur : bk[j];
            dcur  = take ? td : dcur;
            kcur  = take ? tk : kcur;
        }
    }

    // ---- gather argmax class only for the 5 winners; apply cutoff ----
    int votes[KNN];
#pragma unroll
    for (int j = 0; j < KNN; ++j) {
        int k = bk[j];
        const int dz = k / 9 - 1;
        const int dy = (k / 3) % 3 - 1;
        const int dx = k % 3 - 1;
        int zz = z + dz, yy = y + dy, xx = x + dx;
        bool ok = ((unsigned)zz < (unsigned)DIM_D) &
                  ((unsigned)yy < (unsigned)DIM_H) &
                  ((unsigned)xx < (unsigned)DIM_W);
        int zi = ok ? zz : 0;
        int yi = ok ? yy : 0;
        int xi = ok ? xx : 0;
        int cls = pa[((size_t)zi * DIM_H + yi) * DIM_W + xi];
        cls = ok ? cls : 0;                       // zero padding -> class 0
        cls = (bd[j] > 1.0f) ? NCLASSES : cls;    // cutoff -> invalid bucket
        votes[j] = cls;
    }

    // ---- majority vote over classes 1..20, ties -> lowest class ----
    int best_cnt = 0, best_cls = 1;  // all-invalid => argmax(zeros)=0 => +1
#pragma unroll
    for (int j = 0; j < KNN; ++j) {
        int v = votes[j];
        if (v >= 1 && v <= NCLASSES - 1) {
            int cnt = 0;
#pragma unroll
            for (int i = 0; i < KNN; ++i) cnt += (votes[i] == v) ? 1 : 0;
            if (cnt > best_cnt || (cnt == best_cnt && v < best_cls)) {
                best_cnt = cnt;
                best_cls = v;
            }
        }
    }
    out[p] = best_cls;
}

extern "C" void kernel_launch(void* const* d_in, const int* in_sizes, int n_in,
                              void* d_out, int out_size, void* d_ws, size_t ws_size,
                              hipStream_t stream) {
    const float* pr = (const float*)d_in[0];
    const float* ur = (const float*)d_in[1];
    const int*   pa = (const int*)d_in[2];
    const int*   px = (const int*)d_in[3];
    const int*   py = (const int*)d_in[4];
    const int*   pz = (const int*)d_in[5];
    int* out = (int*)d_out;
    int P = in_sizes[1];
    int block = 256;
    int grid = (P + block - 1) / block;
    bev_knn_kernel<<<grid, block, 0, stream>>>(pr, ur, pa, px, py, pz, out, P);
}

// Round 2
// 290.565 us; speedup vs baseline: 1.1481x; 1.1481x over previous
//
#include <hip/hip_runtime.h>
#include <hip/hip_bf16.h>
#include <math.h>

#define KNN 5
#define K3 27
#define CENTER 13
#define NCLASSES 21
#define DIM_D 32
#define DIM_H 128
#define DIM_W 2048

// counting-sort buckets: key = (z*H + y)*16 + (x>>7)  -> 32*128*16 = 65536
#define NBUCKETS 65536
#define SCAN_THREADS 1024
#define CHUNK (NBUCKETS / SCAN_THREADS)   // 64

__device__ __forceinline__ unsigned bucket_key(int x, int y, int z) {
    return ((unsigned)(z * DIM_H + y) << 4) | ((unsigned)x >> 7);
}

__global__ __launch_bounds__(256) void hist_kernel(
    const int* __restrict__ px, const int* __restrict__ py,
    const int* __restrict__ pz, unsigned* __restrict__ hist, int P)
{
    int p = blockIdx.x * blockDim.x + threadIdx.x;
    if (p >= P) return;
    atomicAdd(&hist[bucket_key(px[p], py[p], pz[p])], 1u);
}

// single-block exclusive scan over NBUCKETS (in place), 2-phase chunked
__global__ __launch_bounds__(SCAN_THREADS) void scan_kernel(unsigned* __restrict__ hist)
{
    __shared__ unsigned tmp[SCAN_THREADS];
    int t = threadIdx.x;
    unsigned base = (unsigned)t * CHUNK;
    unsigned loc[CHUNK];
    unsigned s = 0;
#pragma unroll
    for (int j = 0; j < CHUNK; ++j) { loc[j] = hist[base + j]; s += loc[j]; }
    tmp[t] = s;
    __syncthreads();
    // inclusive Hillis-Steele over the 1024 per-thread sums
    for (int off = 1; off < SCAN_THREADS; off <<= 1) {
        unsigned v = (t >= off) ? tmp[t - off] : 0u;
        __syncthreads();
        tmp[t] += v;
        __syncthreads();
    }
    unsigned run = (t == 0) ? 0u : tmp[t - 1];
#pragma unroll
    for (int j = 0; j < CHUNK; ++j) { unsigned v = loc[j]; hist[base + j] = run; run += v; }
}

__global__ __launch_bounds__(256) void scatter_kernel(
    const float* __restrict__ ur, const int* __restrict__ px,
    const int* __restrict__ py, const int* __restrict__ pz,
    unsigned* __restrict__ hist, float* __restrict__ s_u,
    unsigned* __restrict__ s_xyz, int* __restrict__ s_idx, int P)
{
    int p = blockIdx.x * blockDim.x + threadIdx.x;
    if (p >= P) return;
    int x = px[p], y = py[p], z = pz[p];
    unsigned key = bucket_key(x, y, z);
    unsigned pos = atomicAdd(&hist[key], 1u);
    s_u[pos]   = ur[p];
    s_xyz[pos] = (unsigned)x | ((unsigned)y << 11) | ((unsigned)z << 18);
    s_idx[pos] = p;
}

template <bool SORTED>
__global__ __launch_bounds__(256) void bev_knn_kernel(
    const float* __restrict__ pr,   // proj_range  [D,H,W]
    const int*   __restrict__ pa,   // proj_argmax [D,H,W]
    const float* __restrict__ s_u,  // sorted (or raw) unproj_range
    const unsigned* __restrict__ s_xyz,
    const int*   __restrict__ s_idx,
    const int*   __restrict__ rx, const int* __restrict__ ry,
    const int*   __restrict__ rz,
    int*         __restrict__ out, int P)
{
    int p = blockIdx.x * blockDim.x + threadIdx.x;
    if (p >= P) return;

    float u = s_u[p];
    int x, y, z, oidx;
    if (SORTED) {
        unsigned w = s_xyz[p];
        x = (int)(w & 0x7FFu);
        y = (int)((w >> 11) & 0x7Fu);
        z = (int)((w >> 18) & 0x1Fu);
        oidx = s_idx[p];
    } else {
        x = rx[p]; y = ry[p]; z = rz[p]; oidx = p;
    }

    // ---- gather 27 neighbor ranges (clamped addr + select; full MLP) ----
    float dist[K3];
#pragma unroll
    for (int k = 0; k < K3; ++k) {
        const int dz = k / 9 - 1;
        const int dy = (k / 3) % 3 - 1;
        const int dx = k % 3 - 1;
        int zz = z + dz, yy = y + dy, xx = x + dx;
        bool ok = ((unsigned)zz < (unsigned)DIM_D) &
                  ((unsigned)yy < (unsigned)DIM_H) &
                  ((unsigned)xx < (unsigned)DIM_W);
        int zi = ok ? zz : 0;
        int yi = ok ? yy : 0;
        int xi = ok ? xx : 0;
        float r = pr[((size_t)zi * DIM_H + yi) * DIM_W + xi];
        r = ok ? r : 0.0f;              // zero padding
        r = (r < 0.0f) ? INFINITY : r;  // negative-range mask
        float d = fabsf(r - u);
        dist[k] = (k == CENTER) ? 0.0f : d;
    }

    // ---- top-5 smallest, ties -> lower flat index (lax.top_k semantics) ----
    float bd[KNN];
    int   bk[KNN];
#pragma unroll
    for (int j = 0; j < KNN; ++j) { bd[j] = INFINITY; bk[j] = -1; }
#pragma unroll
    for (int k = 0; k < K3; ++k) {
        float dcur = dist[k];
        int   kcur = k;
#pragma unroll
        for (int j = 0; j < KNN; ++j) {
            bool take = dcur < bd[j];
            float td = bd[j]; int tk = bk[j];
            bd[j] = take ? dcur : bd[j];
            bk[j] = take ? kcur : bk[j];
            dcur  = take ? td : dcur;
            kcur  = take ? tk : kcur;
        }
    }

    // ---- gather argmax class only for the 5 winners; apply cutoff ----
    int votes[KNN];
#pragma unroll
    for (int j = 0; j < KNN; ++j) {
        int k = bk[j];
        const int dz = k / 9 - 1;
        const int dy = (k / 3) % 3 - 1;
        const int dx = k % 3 - 1;
        int zz = z + dz, yy = y + dy, xx = x + dx;
        bool ok = ((unsigned)zz < (unsigned)DIM_D) &
                  ((unsigned)yy < (unsigned)DIM_H) &
                  ((unsigned)xx < (unsigned)DIM_W);
        int zi = ok ? zz : 0;
        int yi = ok ? yy : 0;
        int xi = ok ? xx : 0;
        int cls = pa[((size_t)zi * DIM_H + yi) * DIM_W + xi];
        cls = ok ? cls : 0;                       // zero padding -> class 0
        cls = (bd[j] > 1.0f) ? NCLASSES : cls;    // cutoff -> invalid bucket
        votes[j] = cls;
    }

    // ---- majority vote over classes 1..20, ties -> lowest class ----
    int best_cnt = 0, best_cls = 1;  // all-invalid => argmax(zeros)=0 => +1
#pragma unroll
    for (int j = 0; j < KNN; ++j) {
        int v = votes[j];
        if (v >= 1 && v <= NCLASSES - 1) {
            int cnt = 0;
#pragma unroll
            for (int i = 0; i < KNN; ++i) cnt += (votes[i] == v) ? 1 : 0;
            if (cnt > best_cnt || (cnt == best_cnt && v < best_cls)) {
                best_cnt = cnt;
                best_cls = v;
            }
        }
    }
    out[oidx] = best_cls;
}

extern "C" void kernel_launch(void* const* d_in, const int* in_sizes, int n_in,
                              void* d_out, int out_size, void* d_ws, size_t ws_size,
                              hipStream_t stream) {
    const float* pr = (const float*)d_in[0];
    const float* ur = (const float*)d_in[1];
    const int*   pa = (const int*)d_in[2];
    const int*   px = (const int*)d_in[3];
    const int*   py = (const int*)d_in[4];
    const int*   pz = (const int*)d_in[5];
    int* out = (int*)d_out;
    int P = in_sizes[1];
    int block = 256;
    int grid = (P + block - 1) / block;

    // workspace layout: hist | s_u | s_xyz | s_idx
    size_t hist_b = (size_t)NBUCKETS * 4;
    size_t arr_b  = (size_t)P * 4;
    size_t need   = hist_b + 3 * arr_b;

    if (ws_size >= need) {
        char* ws = (char*)d_ws;
        unsigned* hist  = (unsigned*)ws;
        float*    s_u   = (float*)(ws + hist_b);
        unsigned* s_xyz = (unsigned*)(ws + hist_b + arr_b);
        int*      s_idx = (int*)(ws + hist_b + 2 * arr_b);

        hipMemsetAsync(hist, 0, hist_b, stream);
        hist_kernel<<<grid, block, 0, stream>>>(px, py, pz, hist, P);
        scan_kernel<<<1, SCAN_THREADS, 0, stream>>>(hist);
        scatter_kernel<<<grid, block, 0, stream>>>(ur, px, py, pz, hist,
                                                   s_u, s_xyz, s_idx, P);
        bev_knn_kernel<true><<<grid, block, 0, stream>>>(
            pr, pa, s_u, s_xyz, s_idx, nullptr, nullptr, nullptr, out, P);
    } else {
        // fallback: direct unsorted
        bev_knn_kernel<false><<<grid, block, 0, stream>>>(
            pr, pa, ur, nullptr, nullptr, px, py, pz, out, P);
    }
}